// Round 9
// baseline (233.583 us; speedup 1.0000x reference)
//
#include <hip/hip_runtime.h>

#define NEXP 8
#define DIM  1024
#define HID  2048
#define NTOK 8192

#define BM 128
#define BN 128
#define BK 32

typedef short s16x8 __attribute__((ext_vector_type(8)));
typedef float f32x4 __attribute__((ext_vector_type(4)));
typedef unsigned short u16;

__device__ __forceinline__ u16 f2bf(float f) {
  unsigned int u = __builtin_bit_cast(unsigned int, f);
  u += 0x7FFFu + ((u >> 16) & 1u);   // RNE
  return (u16)(u >> 16);
}

// pack 8 f32 -> 8 bf16 (RNE) via v_cvt_pk_bf16_f32 (dst.lo = src0)
__device__ __forceinline__ s16x8 pk8(float4 a, float4 b) {
  union { unsigned u[4]; s16x8 v; } P;
  asm("v_cvt_pk_bf16_f32 %0, %1, %2" : "=v"(P.u[0]) : "v"(a.x), "v"(a.y));
  asm("v_cvt_pk_bf16_f32 %0, %1, %2" : "=v"(P.u[1]) : "v"(a.z), "v"(a.w));
  asm("v_cvt_pk_bf16_f32 %0, %1, %2" : "=v"(P.u[2]) : "v"(b.x), "v"(b.y));
  asm("v_cvt_pk_bf16_f32 %0, %1, %2" : "=v"(P.u[3]) : "v"(b.z), "v"(b.w));
  return P.v;
}

// async global->LDS, 16B per lane; LDS dest is wave-uniform base (HW adds lane*16)
__device__ __forceinline__ void gload16(const u16* g, u16* l) {
  __builtin_amdgcn_global_load_lds((const __attribute__((address_space(1))) void*)g,
                                   (__attribute__((address_space(3))) void*)l, 16, 0, 0);
}

// Flat row-tile scheduler over the 8 experts. Max total row tiles = 64 + 7 < 72.
// Harness passes integer inputs as int32.
__device__ __forceinline__ bool find_tile(const int* __restrict__ cnts, int rt,
                                          int& e_out, int& row0, int& cnt_out, long long& off_out) {
  long long off = 0; int cum = 0;
  #pragma unroll
  for (int e = 0; e < NEXP; ++e) {
    int c = cnts[e];
    int nt = (c + BM - 1) / BM;
    if (rt < cum + nt) { e_out = e; row0 = (rt - cum) * BM; cnt_out = c; off_out = off; return true; }
    cum += nt; off += c;
  }
  return false;
}

// ---------------- GEMM1: fp32 inputs staged directly (reg->cvt->LDS), 8 waves ----------------
// waves 0-3: gate = x@w1^T; waves 4-7: up = x@w3^T (same output subtiles).
// LDS layout identical to R8's verified swizzle: LDS[row][cs] holds global colblk
// cs ^ ((row>>1)&3); fragment read uses lk = ((lane>>4) ^ ((lr>>1)&3))<<3. Bank-conflict 0.
// 2-buffer / 1-barrier pipeline: LOADS(t+1) -> COMPUTE(t) -> cvt+ds_write(t+1) -> barrier.
#define XSTR 68   // f32 LDS stride for up-exchange (2-way bank aliasing only)
__global__ __launch_bounds__(512, 4) void gemm1_f32(
    const float* __restrict__ x, const int* __restrict__ cnts,
    const float* __restrict__ w1, const float* __restrict__ w3,
    u16* __restrict__ hbuf)
{
  int e, row0, cnt; long long off;
  if (!find_tile(cnts, blockIdx.y, e, row0, cnt, off)) return;
  const int ct = blockIdx.x;

  // union: 2 staging bufs (2*3*8KB = 48KB) in loop; up-exchange (69.6KB f32) in epilogue
  __shared__ __align__(16) float smem_f[4 * 64 * XSTR];   // 69632 B -> 2 blocks/CU
  u16* stage = (u16*)smem_f;

  const int t    = threadIdx.x;
  const int lane = t & 63;
  const int wid  = t >> 6;          // 0..7
  const int mat  = wid >> 2;        // 0 = gate/w1, 1 = up/w3
  const int sw   = wid & 3;         // output subtile id
  const int wr = sw >> 1, wc = sw & 1;
  const int lr = lane & 15;
  const int lk = (((lane >> 4) ^ ((lr >> 1) & 3)) << 3);   // swizzled fragment-read offset

  // staging geometry: lane covers (row srow, LDS colblk cs=lane&3) <- global colblk cf
  const int q    = lane >> 2;                 // 0..15
  const int cf   = (lane & 3) ^ ((q >> 1) & 3);
  const int srow = wid * 16 + q;

  const float* xr  = x  + (size_t)(off + row0) * DIM;   // overreads stay inside x alloc
  const float* w1t = w1 + ((size_t)e * HID + (size_t)ct * BN) * DIM;
  const float* w3t = w3 + ((size_t)e * HID + (size_t)ct * BN) * DIM;
  const size_t gbase = (size_t)srow * DIM + cf * 8;

  f32x4 acc[4][4];
  const f32x4 zf = {0.f, 0.f, 0.f, 0.f};
  #pragma unroll
  for (int i = 0; i < 4; ++i)
    #pragma unroll
    for (int j = 0; j < 4; ++j) acc[i][j] = zf;

  float4 Ra0, Ra1, Rb0, Rb1, Rc0, Rc1;   // in-flight fp32 (24 VGPR)
  auto LOADS = [&](int k0) {
    const size_t go = gbase + k0;
    Ra0 = *(const float4*)&xr [go]; Ra1 = *(const float4*)&xr [go + 4];
    Rb0 = *(const float4*)&w1t[go]; Rb1 = *(const float4*)&w1t[go + 4];
    Rc0 = *(const float4*)&w3t[go]; Rc1 = *(const float4*)&w3t[go + 4];
  };
  auto WRITE = [&](int b) {    // cvt + 3 ds_write_b128, lane-linear dest (same addrs as gload_lds)
    u16* base = stage + b * (3 * 4096) + wid * 512 + lane * 8;
    *(s16x8*)(base)        = pk8(Ra0, Ra1);
    *(s16x8*)(base + 4096) = pk8(Rb0, Rb1);
    *(s16x8*)(base + 8192) = pk8(Rc0, Rc1);
  };
  auto COMPUTE = [&](int b) {
    const u16* Asb = stage + b * (3 * 4096);
    const u16* Bsb = Asb + 4096 + mat * 4096;         // wave-uniform w1/w3 select
    s16x8 af[4], bf[4];
    #pragma unroll
    for (int fm = 0; fm < 4; ++fm)
      af[fm] = *(const s16x8*)&Asb[(wr * 64 + fm * 16 + lr) * BK + lk];
    #pragma unroll
    for (int fn = 0; fn < 4; ++fn)
      bf[fn] = *(const s16x8*)&Bsb[(wc * 64 + fn * 16 + lr) * BK + lk];
    __builtin_amdgcn_s_setprio(1);
    #pragma unroll
    for (int fm = 0; fm < 4; ++fm)
      #pragma unroll
      for (int fn = 0; fn < 4; ++fn)
        acc[fm][fn] = __builtin_amdgcn_mfma_f32_16x16x32_bf16(af[fm], bf[fn], acc[fm][fn], 0, 0, 0);
    __builtin_amdgcn_s_setprio(0);
  };

  const int NT = DIM / BK;   // 32
  LOADS(0);
  WRITE(0);
  __syncthreads();
  int cur = 0;
  for (int kt = 0; kt < NT - 1; ++kt) {
    LOADS((kt + 1) * BK);    // issue early: HBM latency hides under ds_read+MFMA
    COMPUTE(cur);
    WRITE(cur ^ 1);          // buf[cur^1]'s readers finished before previous barrier
    __syncthreads();         // publishes writes; drains vmcnt/lgkm
    cur ^= 1;
  }
  COMPUTE(cur);

  // ---- epilogue: exchange up via LDS, fuse silu(g)*u, store bf16 h ----
  __syncthreads();   // all waves' LDS reads done before smem reuse
  if (mat) {
    float* up = smem_f + sw * (64 * XSTR);
    #pragma unroll
    for (int fm = 0; fm < 4; ++fm)
      #pragma unroll
      for (int fn = 0; fn < 4; ++fn)
        #pragma unroll
        for (int j = 0; j < 4; ++j)
          up[(fm * 16 + ((lane >> 4) << 2) + j) * XSTR + fn * 16 + lr] = acc[fm][fn][j];
  }
  __syncthreads();
  if (!mat) {
    const float* up = smem_f + sw * (64 * XSTR);
    #pragma unroll
    for (int fm = 0; fm < 4; ++fm)
      #pragma unroll
      for (int fn = 0; fn < 4; ++fn) {
        const int col = ct * BN + wc * 64 + fn * 16 + lr;
        #pragma unroll
        for (int j = 0; j < 4; ++j) {
          const int r = wr * 64 + fm * 16 + ((lane >> 4) << 2) + j;
          if (row0 + r < cnt) {
            const float gv = acc[fm][fn][j];
            const float uv = up[(fm * 16 + ((lane >> 4) << 2) + j) * XSTR + fn * 16 + lr];
            const float hv = (gv / (1.f + __expf(-gv))) * uv;
            hbuf[(size_t)(off + row0 + r) * HID + col] = f2bf(hv);
          }
        }
      }
  }
}

// ---------------- GEMM2: A = h bf16 via gload_lds, B = w2 fp32 reg-staged ----------------
__global__ __launch_bounds__(256, 4) void gemm2_f32(
    const u16* __restrict__ hbuf, const int* __restrict__ cnts,
    const float* __restrict__ w2, float* __restrict__ out)
{
  int e, row0, cnt; long long off;
  if (!find_tile(cnts, blockIdx.y, e, row0, cnt, off)) return;
  const int ct = blockIdx.x;

  __shared__ __align__(16) u16 stage[2 * 2 * 4096];   // 32 KB: [2 bufs][A,B][4096]

  const int t    = threadIdx.x;
  const int lane = t & 63;
  const int wid  = t >> 6;          // 0..3
  const int wr = wid >> 1, wc = wid & 1;
  const int lr = lane & 15;
  const int lk = (((lane >> 4) ^ ((lr >> 1) & 3)) << 3);

  const int q  = lane >> 2;
  const int cf = (lane & 3) ^ ((q >> 1) & 3);

  const u16* ar    = hbuf + (size_t)(off + row0) * HID;   // stale rows beyond cnt are finite
  const float* w2t = w2 + ((size_t)e * DIM + (size_t)ct * BN) * HID;

  f32x4 acc[4][4];
  const f32x4 zf = {0.f, 0.f, 0.f, 0.f};
  #pragma unroll
  for (int i = 0; i < 4; ++i)
    #pragma unroll
    for (int j = 0; j < 4; ++j) acc[i][j] = zf;

  float4 Rb[4];   // w2 in-flight (16 VGPR)
  auto LOADS = [&](int k0, int b) {   // A: 2 gload_lds (DMA to buf b); B: 4 dwordx4 -> regs
    u16* Abase = stage + b * (2 * 4096);
    #pragma unroll
    for (int c = 0; c < 2; ++c) {
      const int chunk = wid * 2 + c;
      const int r = chunk * 16 + q;
      const size_t go = (size_t)r * HID + k0 + cf * 8;
      gload16(&ar[go], Abase + chunk * 512);
      Rb[2 * c]     = *(const float4*)&w2t[go];
      Rb[2 * c + 1] = *(const float4*)&w2t[go + 4];
    }
  };
  auto WRITEB = [&](int b) {
    u16* Bbase = stage + b * (2 * 4096) + 4096;
    *(s16x8*)(Bbase + (wid * 2 + 0) * 512 + lane * 8) = pk8(Rb[0], Rb[1]);
    *(s16x8*)(Bbase + (wid * 2 + 1) * 512 + lane * 8) = pk8(Rb[2], Rb[3]);
  };
  auto COMPUTE = [&](int b) {
    const u16* Asb = stage + b * (2 * 4096);
    const u16* Bsb = Asb + 4096;
    s16x8 af[4], bf[4];
    #pragma unroll
    for (int fm = 0; fm < 4; ++fm)
      af[fm] = *(const s16x8*)&Asb[(wr * 64 + fm * 16 + lr) * BK + lk];
    #pragma unroll
    for (int fn = 0; fn < 4; ++fn)
      bf[fn] = *(const s16x8*)&Bsb[(wc * 64 + fn * 16 + lr) * BK + lk];
    #pragma unroll
    for (int fm = 0; fm < 4; ++fm)
      #pragma unroll
      for (int fn = 0; fn < 4; ++fn)
        acc[fm][fn] = __builtin_amdgcn_mfma_f32_16x16x32_bf16(af[fm], bf[fn], acc[fm][fn], 0, 0, 0);
  };

  const int NT = HID / BK;   // 64
  LOADS(0, 0);
  WRITEB(0);
  __syncthreads();
  int cur = 0;
  for (int kt = 0; kt < NT - 1; ++kt) {
    LOADS((kt + 1) * BK, cur ^ 1);   // DMA A directly into buf[cur^1]; B to regs
    COMPUTE(cur);
    WRITEB(cur ^ 1);
    __syncthreads();
    cur ^= 1;
  }
  COMPUTE(cur);

  #pragma unroll
  for (int fm = 0; fm < 4; ++fm)
    #pragma unroll
    for (int fn = 0; fn < 4; ++fn) {
      const int col = ct * BN + wc * 64 + fn * 16 + lr;
      #pragma unroll
      for (int j = 0; j < 4; ++j) {
        const int r = wr * 64 + fm * 16 + ((lane >> 4) << 2) + j;
        if (row0 + r < cnt)
          out[(size_t)(off + row0 + r) * DIM + col] = acc[fm][fn][j];
      }
    }
}

// Zero padding rows [total, NTOK) — d_out poisoned once, not re-poisoned between replays.
__global__ void zero_pad_kernel(const int* __restrict__ cnts, float* __restrict__ out)
{
  int total = 0;
  #pragma unroll
  for (int e = 0; e < NEXP; ++e) total += cnts[e];
  const int row = blockIdx.x;
  if (row < total) return;
  float4* p = (float4*)(out + (size_t)row * DIM);
  p[threadIdx.x] = make_float4(0.f, 0.f, 0.f, 0.f);
}

extern "C" void kernel_launch(void* const* d_in, const int* in_sizes, int n_in,
                              void* d_out, int out_size, void* d_ws, size_t ws_size,
                              hipStream_t stream) {
  const float* x    = (const float*)d_in[0];
  const int*   cnts = (const int*)d_in[1];
  const float* w1   = (const float*)d_in[2];
  const float* w2   = (const float*)d_in[3];
  const float* w3   = (const float*)d_in[4];
  float*       out  = (float*)d_out;

  u16* hbuf = (u16*)d_ws;   // NTOK*HID bf16 = 33.5 MB (only workspace needed now)

  gemm1_f32<<<dim3(HID / BN, 72), dim3(512), 0, stream>>>(x, cnts, w1, w3, hbuf);
  gemm2_f32<<<dim3(DIM / BN, 72), dim3(256), 0, stream>>>(hbuf, cnts, w2, out);
  zero_pad_kernel<<<dim3(NTOK), dim3(256), 0, stream>>>(cnts, out);
}

// Round 10
// 202.581 us; speedup vs baseline: 1.1530x; 1.1530x over previous
//
#include <hip/hip_runtime.h>

#define NEXP 8
#define DIM  1024
#define HID  2048
#define NTOK 8192

#define BM 128
#define BN 128
#define BK 32

typedef short s16x8 __attribute__((ext_vector_type(8)));
typedef float f32x4 __attribute__((ext_vector_type(4)));
typedef unsigned short u16;

__device__ __forceinline__ u16 f2bf(float f) {
  unsigned int u = __builtin_bit_cast(unsigned int, f);
  u += 0x7FFFu + ((u >> 16) & 1u);   // RNE
  return (u16)(u >> 16);
}

__device__ __forceinline__ ushort4 cvt4(float4 a) {
  ushort4 r; r.x = f2bf(a.x); r.y = f2bf(a.y); r.z = f2bf(a.z); r.w = f2bf(a.w); return r;
}

// pack 8 f32 -> 8 bf16 (RNE) via v_cvt_pk_bf16_f32
__device__ __forceinline__ s16x8 pk8(float4 a, float4 b) {
  union { unsigned u[4]; s16x8 v; } P;
  asm("v_cvt_pk_bf16_f32 %0, %1, %2" : "=v"(P.u[0]) : "v"(a.x), "v"(a.y));
  asm("v_cvt_pk_bf16_f32 %0, %1, %2" : "=v"(P.u[1]) : "v"(a.z), "v"(a.w));
  asm("v_cvt_pk_bf16_f32 %0, %1, %2" : "=v"(P.u[2]) : "v"(b.x), "v"(b.y));
  asm("v_cvt_pk_bf16_f32 %0, %1, %2" : "=v"(P.u[3]) : "v"(b.z), "v"(b.w));
  return P.v;
}

// async global->LDS, 16B per lane; LDS dest is wave-uniform base (HW adds lane*16)
__device__ __forceinline__ void gload16(const u16* g, u16* l) {
  __builtin_amdgcn_global_load_lds((const __attribute__((address_space(1))) void*)g,
                                   (__attribute__((address_space(3))) void*)l, 16, 0, 0);
}

// raw barrier: NO vmcnt drain (keeps async loads in flight); lgkmcnt(0) publishes ds_writes
__device__ __forceinline__ void BAR() {
  asm volatile("s_waitcnt lgkmcnt(0)" ::: "memory");
  __builtin_amdgcn_s_barrier();
  asm volatile("" ::: "memory");
}

// Flat row-tile scheduler over the 8 experts. Max total row tiles = 64 + 7 < 72.
// Harness passes integer inputs as int32.
__device__ __forceinline__ bool find_tile(const int* __restrict__ cnts, int rt,
                                          int& e_out, int& row0, int& cnt_out, long long& off_out) {
  long long off = 0; int cum = 0;
  #pragma unroll
  for (int e = 0; e < NEXP; ++e) {
    int c = cnts[e];
    int nt = (c + BM - 1) / BM;
    if (rt < cum + nt) { e_out = e; row0 = (rt - cum) * BM; cnt_out = c; off_out = off; return true; }
    cum += nt; off += c;
  }
  return false;
}

// ---------------- cvt_x: x fp32 -> bf16 (33.5 MB read, ~10 us) ----------------
__global__ __launch_bounds__(256) void cvt_x(const float* __restrict__ in,
                                             u16* __restrict__ out, int n4) {
  const int i = blockIdx.x * 256 + threadIdx.x;
  if (i < n4) ((ushort4*)out)[i] = cvt4(((const float4*)in)[i]);
}

// ---------------- GEMM1: A = x bf16 via gload_lds (3-buf, 2-ahead); w1/w3 fp32 reg-staged ----------------
// 8 waves: 0-3 gate = x@w1^T, 4-7 up = x@w3^T (same output subtiles).
// LDS (u16 units): A bufs ab*4096 (3x8KB); W bufs 12288 + wb*8192 (w1 +0, w3 +4096) (2x16KB). 56KB.
// Swizzle (proven R8): global colblk cf=(lane&3)^((q>>1)&3) -> linear LDS; read lk=((lane>>4)^((lr>>1)&3))<<3.
#define XSTR 68
__global__ __launch_bounds__(512, 4) void gemm1_hyb(
    const u16* __restrict__ xb, const int* __restrict__ cnts,
    const float* __restrict__ w1, const float* __restrict__ w3,
    u16* __restrict__ hbuf)
{
  int e, row0, cnt; long long off;
  if (!find_tile(cnts, blockIdx.y, e, row0, cnt, off)) return;
  const int ct = blockIdx.x;

  __shared__ __align__(16) float smem_f[4 * 64 * XSTR];   // 69632 B union
  u16* lds = (u16*)smem_f;

  const int t    = threadIdx.x;
  const int lane = t & 63;
  const int wid  = t >> 6;
  const int mat  = wid >> 2;
  const int sw   = wid & 3;
  const int wr = sw >> 1, wc = sw & 1;
  const int lr = lane & 15;
  const int lk = (((lane >> 4) ^ ((lr >> 1) & 3)) << 3);

  const int q    = lane >> 2;
  const int cf   = (lane & 3) ^ ((q >> 1) & 3);
  const int srow = wid * 16 + q;

  const u16*   xr  = xb + (size_t)(off + row0) * DIM;   // overreads stay in-bounds
  const float* w1t = w1 + ((size_t)e * HID + (size_t)ct * BN) * DIM;
  const float* w3t = w3 + ((size_t)e * HID + (size_t)ct * BN) * DIM;
  const size_t gaoff = (size_t)srow * DIM + cf * 8;

  f32x4 acc[4][4];
  const f32x4 zf = {0.f, 0.f, 0.f, 0.f};
  #pragma unroll
  for (int i = 0; i < 4; ++i)
    #pragma unroll
    for (int j = 0; j < 4; ++j) acc[i][j] = zf;

  float4 S[4];   // single w-set: {w1 lo/hi, w3 lo/hi}
  auto ADMA = [&](int k0, int ab) {     // issued FIRST in each stage (older than w-loads)
    gload16(&xr[gaoff + k0], lds + ab * 4096 + wid * 512);
  };
  auto WLOAD = [&](int k0) {
    const size_t go = gaoff + k0;
    S[0] = *(const float4*)&w1t[go]; S[1] = *(const float4*)&w1t[go + 4];
    S[2] = *(const float4*)&w3t[go]; S[3] = *(const float4*)&w3t[go + 4];
  };
  auto WRITE_W = [&](int wb) {          // compiler auto-waits vmcnt for S (precise count)
    u16* base = lds + 12288 + wb * 8192 + wid * 512 + lane * 8;
    *(s16x8*)(base)        = pk8(S[0], S[1]);
    *(s16x8*)(base + 4096) = pk8(S[2], S[3]);
  };
  auto COMPUTE = [&](int ab, int wb) {
    const u16* Asb = lds + ab * 4096;
    const u16* Bsb = lds + 12288 + wb * 8192 + mat * 4096;
    s16x8 af[4], bf[4];
    #pragma unroll
    for (int fm = 0; fm < 4; ++fm)
      af[fm] = *(const s16x8*)&Asb[(wr * 64 + fm * 16 + lr) * BK + lk];
    #pragma unroll
    for (int fn = 0; fn < 4; ++fn)
      bf[fn] = *(const s16x8*)&Bsb[(wc * 64 + fn * 16 + lr) * BK + lk];
    __builtin_amdgcn_s_setprio(1);
    #pragma unroll
    for (int fm = 0; fm < 4; ++fm)
      #pragma unroll
      for (int fn = 0; fn < 4; ++fn)
        acc[fm][fn] = __builtin_amdgcn_mfma_f32_16x16x32_bf16(af[fm], bf[fn], acc[fm][fn], 0, 0, 0);
    __builtin_amdgcn_s_setprio(0);
  };

  const int NT = DIM / BK;   // 32
  // prologue: A(0),A(1) DMA; w(0)->S; WRITE_W forces A(0),A(1),w(0) complete (in-order vmcnt); w(1)->S
  ADMA(0, 0);
  ADMA(BK, 1);
  WLOAD(0);
  WRITE_W(0);
  WLOAD(BK);
  BAR();
  for (int kt = 0; kt < NT; ++kt) {
    if (kt + 2 < NT) ADMA((kt + 2) * BK, (kt + 2) % 3);
    COMPUTE(kt % 3, kt & 1);
    if (kt + 1 < NT) {
      WRITE_W((kt + 1) & 1);                 // w(kt+1); auto-wait also proves A(kt+1) landed
      if (kt + 2 < NT) WLOAD((kt + 2) * BK); // reload S after consumption: 1-iter cover
    }
    BAR();
  }

  // ---- epilogue: exchange up via LDS, fuse silu(g)*u, store bf16 h ----
  __syncthreads();
  if (mat) {
    float* up = smem_f + sw * (64 * XSTR);
    #pragma unroll
    for (int fm = 0; fm < 4; ++fm)
      #pragma unroll
      for (int fn = 0; fn < 4; ++fn)
        #pragma unroll
        for (int j = 0; j < 4; ++j)
          up[(fm * 16 + ((lane >> 4) << 2) + j) * XSTR + fn * 16 + lr] = acc[fm][fn][j];
  }
  __syncthreads();
  if (!mat) {
    const float* up = smem_f + sw * (64 * XSTR);
    #pragma unroll
    for (int fm = 0; fm < 4; ++fm)
      #pragma unroll
      for (int fn = 0; fn < 4; ++fn) {
        const int col = ct * BN + wc * 64 + fn * 16 + lr;
        #pragma unroll
        for (int j = 0; j < 4; ++j) {
          const int r = wr * 64 + fm * 16 + ((lane >> 4) << 2) + j;
          if (row0 + r < cnt) {
            const float gv = acc[fm][fn][j];
            const float uv = up[(fm * 16 + ((lane >> 4) << 2) + j) * XSTR + fn * 16 + lr];
            const float hv = (gv / (1.f + __expf(-gv))) * uv;
            hbuf[(size_t)(off + row0 + r) * HID + col] = f2bf(hv);
          }
        }
      }
  }
}

// ---------------- GEMM2: A = h bf16 via gload_lds (3-buf, 2-ahead); w2 fp32 reg-staged ----------------
__global__ __launch_bounds__(256, 4) void gemm2_hyb(
    const u16* __restrict__ hbuf, const int* __restrict__ cnts,
    const float* __restrict__ w2, float* __restrict__ out)
{
  int e, row0, cnt; long long off;
  if (!find_tile(cnts, blockIdx.y, e, row0, cnt, off)) return;
  const int ct = blockIdx.x;

  __shared__ __align__(16) u16 lds[20480];   // A 3x4096 + B 2x4096 = 40 KB

  const int t    = threadIdx.x;
  const int lane = t & 63;
  const int wid  = t >> 6;
  const int wr = wid >> 1, wc = wid & 1;
  const int lr = lane & 15;
  const int lk = (((lane >> 4) ^ ((lr >> 1) & 3)) << 3);

  const int q  = lane >> 2;
  const int cf = (lane & 3) ^ ((q >> 1) & 3);

  const u16*   ar  = hbuf + (size_t)(off + row0) * HID;   // stale rows beyond cnt are finite
  const float* w2t = w2 + ((size_t)e * DIM + (size_t)ct * BN) * HID;
  const size_t g0 = (size_t)(wid * 32 + q) * HID + cf * 8;        // chunk c=0 row
  const size_t g1 = (size_t)(wid * 32 + 16 + q) * HID + cf * 8;   // chunk c=1 row

  f32x4 acc[4][4];
  const f32x4 zf = {0.f, 0.f, 0.f, 0.f};
  #pragma unroll
  for (int i = 0; i < 4; ++i)
    #pragma unroll
    for (int j = 0; j < 4; ++j) acc[i][j] = zf;

  float4 S[4];
  auto ADMA = [&](int k0, int ab) {
    u16* base = lds + ab * 4096;
    gload16(&ar[g0 + k0], base + (wid * 2 + 0) * 512);
    gload16(&ar[g1 + k0], base + (wid * 2 + 1) * 512);
  };
  auto WLOAD = [&](int k0) {
    S[0] = *(const float4*)&w2t[g0 + k0]; S[1] = *(const float4*)&w2t[g0 + k0 + 4];
    S[2] = *(const float4*)&w2t[g1 + k0]; S[3] = *(const float4*)&w2t[g1 + k0 + 4];
  };
  auto WRITE_W = [&](int wb) {
    u16* base = lds + 12288 + wb * 4096;
    *(s16x8*)(base + (wid * 2 + 0) * 512 + lane * 8) = pk8(S[0], S[1]);
    *(s16x8*)(base + (wid * 2 + 1) * 512 + lane * 8) = pk8(S[2], S[3]);
  };
  auto COMPUTE = [&](int ab, int wb) {
    const u16* Asb = lds + ab * 4096;
    const u16* Bsb = lds + 12288 + wb * 4096;
    s16x8 af[4], bf[4];
    #pragma unroll
    for (int fm = 0; fm < 4; ++fm)
      af[fm] = *(const s16x8*)&Asb[(wr * 64 + fm * 16 + lr) * BK + lk];
    #pragma unroll
    for (int fn = 0; fn < 4; ++fn)
      bf[fn] = *(const s16x8*)&Bsb[(wc * 64 + fn * 16 + lr) * BK + lk];
    #pragma unroll
    for (int fm = 0; fm < 4; ++fm)
      #pragma unroll
      for (int fn = 0; fn < 4; ++fn)
        acc[fm][fn] = __builtin_amdgcn_mfma_f32_16x16x32_bf16(af[fm], bf[fn], acc[fm][fn], 0, 0, 0);
  };

  const int NT = HID / BK;   // 64
  ADMA(0, 0);
  ADMA(BK, 1);
  WLOAD(0);
  WRITE_W(0);
  WLOAD(BK);
  BAR();
  for (int kt = 0; kt < NT; ++kt) {
    if (kt + 2 < NT) ADMA((kt + 2) * BK, (kt + 2) % 3);
    COMPUTE(kt % 3, kt & 1);
    if (kt + 1 < NT) {
      WRITE_W((kt + 1) & 1);
      if (kt + 2 < NT) WLOAD((kt + 2) * BK);
    }
    BAR();
  }

  #pragma unroll
  for (int fm = 0; fm < 4; ++fm)
    #pragma unroll
    for (int fn = 0; fn < 4; ++fn) {
      const int col = ct * BN + wc * 64 + fn * 16 + lr;
      #pragma unroll
      for (int j = 0; j < 4; ++j) {
        const int r = wr * 64 + fm * 16 + ((lane >> 4) << 2) + j;
        if (row0 + r < cnt)
          out[(size_t)(off + row0 + r) * DIM + col] = acc[fm][fn][j];
      }
    }
}

// Zero padding rows [total, NTOK) — d_out poisoned once, not re-poisoned between replays.
__global__ void zero_pad_kernel(const int* __restrict__ cnts, float* __restrict__ out)
{
  int total = 0;
  #pragma unroll
  for (int e = 0; e < NEXP; ++e) total += cnts[e];
  const int row = blockIdx.x;
  if (row < total) return;
  float4* p = (float4*)(out + (size_t)row * DIM);
  p[threadIdx.x] = make_float4(0.f, 0.f, 0.f, 0.f);
}

extern "C" void kernel_launch(void* const* d_in, const int* in_sizes, int n_in,
                              void* d_out, int out_size, void* d_ws, size_t ws_size,
                              hipStream_t stream) {
  const float* x    = (const float*)d_in[0];
  const int*   cnts = (const int*)d_in[1];
  const float* w1   = (const float*)d_in[2];
  const float* w2   = (const float*)d_in[3];
  const float* w3   = (const float*)d_in[4];
  float*       out  = (float*)d_out;

  u16* hbuf = (u16*)d_ws;                          // 33.5 MB
  u16* xb   = hbuf + (size_t)NTOK * HID;           // 16.8 MB

  const int X4 = NTOK * DIM / 4;                   // float4 units
  cvt_x<<<dim3(X4 / 256), dim3(256), 0, stream>>>(x, xb, X4);
  gemm1_hyb<<<dim3(HID / BN, 72), dim3(512), 0, stream>>>(xb, cnts, w1, w3, hbuf);
  gemm2_hyb<<<dim3(DIM / BN, 72), dim3(256), 0, stream>>>(hbuf, cnts, w2, out);
  zero_pad_kernel<<<dim3(NTOK), dim3(256), 0, stream>>>(cnts, out);
}